// Round 4
// baseline (548.811 us; speedup 1.0000x reference)
//
#include <hip/hip_runtime.h>
#include <math.h>

#define NM   50
#define NB   128
#define NL   3
#define NCLS 10

#define PI_D        3.14159265358979323846264338327950288
#define TWO_PI_D    6.28318530717958647692528676655900577
#define INV_2PI_D   0.159154943091895335768883763372514362
#define LAMBDA_D    5.32e-07
#define DIST_D      0.035
#define PLD_D       (PI_D * LAMBDA_D * DIST_D)
#define KD_D        (TWO_PI_D / LAMBDA_D * DIST_D)

// Unified LDS swizzle: element (r,c) lives at r*64 + (c ^ ((r&3)<<2) ^ ((c>>4)&3)).
// Verified: every access pattern in this kernel (transpose W/R both directions,
// staging W/R, intensity W, FC R) hits 16 distinct bank-pairs (b64) / banks (b32)
// within each 16-lane group -> minimum LDS passes, conflict-free.
__device__ __forceinline__ int sw(int r, int c) {
    return r * 64 + (c ^ (((r & 3) << 2) ^ ((c >> 4) & 3)));
}

__host__ __device__ constexpr int rev4(int i) {
    return ((i & 1) << 3) | ((i & 2) << 1) | ((i & 4) >> 1) | ((i & 8) >> 3);
}

__device__ __forceinline__ float dppx1(float v) {  // lane ^ 1 within quad
    return __int_as_float(__builtin_amdgcn_mov_dpp(__float_as_int(v), 0xB1, 0xF, 0xF, true));
}
__device__ __forceinline__ float dppx2(float v) {  // lane ^ 2 within quad
    return __int_as_float(__builtin_amdgcn_mov_dpp(__float_as_int(v), 0x4E, 0xF, 0xF, true));
}

__device__ __forceinline__ void cmul(float& ar, float& ai, float wr, float wi) {
    float r = ar * wr - ai * wi;
    ai = ar * wi + ai * wr;
    ar = r;
}

__device__ __forceinline__ constexpr float c16t(int tw) {
    return (tw == 1) ? 0.923879532511286756f : (tw == 2) ? 0.707106781186547524f :
           (tw == 3) ? 0.382683432365089772f : (tw == 5) ? -0.382683432365089772f :
           (tw == 6) ? -0.707106781186547524f : (tw == 7) ? -0.923879532511286756f : 1.0f;
}
__device__ __forceinline__ constexpr float s16t(int tw) {
    return (tw == 1) ? 0.382683432365089772f : (tw == 2) ? 0.707106781186547524f :
           (tw == 3) ? 0.923879532511286756f : (tw == 5) ? 0.923879532511286756f :
           (tw == 6) ? 0.707106781186547524f : (tw == 7) ? 0.382683432365089772f : 0.0f;
}

// in-place DIF-16, natural in, bit-reversed out (pos i holds X[rev4(i)]), e^{-i}.
__device__ __forceinline__ void dif16_fwd(float* xr, float* xi) {
#pragma unroll
    for (int len = 8; len >= 1; len >>= 1) {
#pragma unroll
        for (int base = 0; base < 16; base += 2 * len) {
#pragma unroll
            for (int j = 0; j < len; j++) {
                const int i0 = base + j, i1 = i0 + len;
                const int tw = j * (8 / len);
                float ar = xr[i0], ai = xi[i0];
                float br = xr[i1], bi = xi[i1];
                xr[i0] = ar + br; xi[i0] = ai + bi;
                float dr = ar - br, di = ai - bi;
                if (tw == 0)      { xr[i1] = dr;  xi[i1] = di; }
                else if (tw == 4) { xr[i1] = di;  xi[i1] = -dr; }           // * (-i)
                else { xr[i1] = dr * c16t(tw) - di * (-s16t(tw));
                       xi[i1] = dr * (-s16t(tw)) + di * c16t(tw); }
            }
        }
    }
}

// in-place DIT-16, bit-reversed in, natural out, e^{+i}, unscaled.
__device__ __forceinline__ void dit16_inv(float* xr, float* xi) {
#pragma unroll
    for (int len = 1; len <= 8; len <<= 1) {
#pragma unroll
        for (int base = 0; base < 16; base += 2 * len) {
#pragma unroll
            for (int j = 0; j < len; j++) {
                const int i0 = base + j, i1 = i0 + len;
                const int tw = j * (8 / len);
                float br = xr[i1], bi = xi[i1];
                if (tw == 4)      { float tp = br; br = -bi; bi = tp; }     // * (+i)
                else if (tw != 0) { float r = br * c16t(tw) - bi * s16t(tw);
                                    bi = br * s16t(tw) + bi * c16t(tw); br = r; }
                float ar = xr[i0], ai = xi[i0];
                xr[i0] = ar + br; xi[i0] = ai + bi;
                xr[i1] = ar - br; xi[i1] = ai - bi;
            }
        }
    }
}

// W64^{t*k} via register chain (no LDS). DIR=+1: conj (fwd), DIR=-1: normal (inv).
template<int DIR>
__device__ __forceinline__ void twiddle_chain(float* xr, float* xi, float w1r, float w1s) {
    const float wi1 = (DIR > 0) ? -w1s : w1s;
    float wr = w1r, wi = wi1;
#pragma unroll
    for (int k = 1; k < 16; k++) {
        const int i = rev4(k);
        cmul(xr[i], xi[i], wr, wi);
        if (k < 15) {
            float nr = wr * w1r - wi * wi1;
            wi = wr * wi1 + wi * w1r;
            wr = nr;
        }
    }
}

// forward cross-quad 4-pt DFT: stage xor2, lane3 *(-i), stage xor1.
__device__ __forceinline__ void quad_fwd(float* xr, float* xi, int t) {
    const float s2 = (t & 2) ? -1.f : 1.f;
    const float s1 = (t & 1) ? -1.f : 1.f;
    const bool l3 = (t == 3);
#pragma unroll
    for (int i = 0; i < 16; i++) {
        float pr = dppx2(xr[i]), pi = dppx2(xi[i]);
        float r = fmaf(xr[i], s2, pr), m = fmaf(xi[i], s2, pi);
        float r2 = l3 ? m : r, m2 = l3 ? -r : m;
        pr = dppx1(r2); pi = dppx1(m2);
        xr[i] = fmaf(r2, s1, pr); xi[i] = fmaf(m2, s1, pi);
    }
}

// inverse cross-quad 4-pt DFT: stage xor1, lane3 *(+i), stage xor2 (unscaled).
__device__ __forceinline__ void quad_inv(float* xr, float* xi, int t) {
    const float s2 = (t & 2) ? -1.f : 1.f;
    const float s1 = (t & 1) ? -1.f : 1.f;
    const bool l3 = (t == 3);
#pragma unroll
    for (int i = 0; i < 16; i++) {
        float pr = dppx1(xr[i]), pi = dppx1(xi[i]);
        float r = fmaf(xr[i], s1, pr), m = fmaf(xi[i], s1, pi);
        float r2 = l3 ? -m : r, m2 = l3 ? r : m;
        pr = dppx2(r2); pi = dppx2(m2);
        xr[i] = fmaf(r2, s2, pr); xi[i] = fmaf(m2, s2, pi);
    }
}

__device__ __forceinline__ void fwd64(float* xr, float* xi, float w1r, float w1s, int t) {
    dif16_fwd(xr, xi);
    twiddle_chain<1>(xr, xi, w1r, w1s);
    quad_fwd(xr, xi, t);
}
__device__ __forceinline__ void inv64(float* xr, float* xi, float w1r, float w1s, int t) {
    quad_inv(xr, xi, t);
    twiddle_chain<-1>(xr, xi, w1r, w1s);
    dit16_inv(xr, xi);
}

// ---------- pre-kernel: phase cos/sin in per-thread layout + H tables ----------
__global__ __launch_bounds__(256) void donn_tables(
    const float* __restrict__ phase, float2* __restrict__ ws)
{
    const int id = blockIdx.x * 256 + threadIdx.x;   // 48*256 = 12288
    if (id < NL * 4096) {
        const int l = id >> 12, rr = id & 4095;
        const int tidm = rr >> 4, j = rr & 15;
        const int g = tidm >> 2, t = tidm & 3;
        float ph = phase[l * 4096 + g * 64 + 4 * j + t];
        float s, c;
        sincosf(ph, &s, &c);
        ws[id] = make_float2(c, s);
    }
    if (id < 128) {
        const int q = id & 63;
        double f = (double)((q < 32) ? q : q - 64) * 15625.0;
        double phd = -PLD_D * f * f;
        if (id < 64) {
            double r1 = phd - TWO_PI_D * rint(phd * INV_2PI_D);
            ws[NL * 4096 + id] = make_float2((float)cos(r1), (float)sin(r1));
        } else {
            double r2 = phd + KD_D;
            r2 = r2 - TWO_PI_D * rint(r2 * INV_2PI_D);
            ws[NL * 4096 + id] = make_float2((float)cos(r2) * (1.0f / 4096.0f),
                                             (float)sin(r2) * (1.0f / 4096.0f));
        }
    }
}

// ---------- main kernel ----------
__global__ __launch_bounds__(256) void donn_main(
    const float* __restrict__ x,
    const float* __restrict__ sre,
    const float* __restrict__ sim,
    const float2* __restrict__ ws,
    const float* __restrict__ fcw,
    const float* __restrict__ fcb,
    float* __restrict__ out)
{
    __shared__ float2 xb2[4096];
    __shared__ float2 hx2[64], hy2[64];

    const int tid = threadIdx.x;
    const int bid = blockIdx.x;
    const int b = bid & (NB - 1);
    const int m = bid >> 7;
    const int g = tid >> 2, t = tid & 3;
    const int sig = ((t & 1) << 1) | (t >> 1);

    // H tables: 2 coalesced b64 loads by wave 0 (barrier #1 publishes them)
    if (tid < 64) {
        hx2[tid] = ws[NL * 4096 + tid];
        hy2[tid] = ws[NL * 4096 + 64 + tid];
    }

    // per-thread base twiddle W64^t, reused by every fft64
    float w1r, w1s;
    sincosf((float)t * (float)(TWO_PI_D / 64.0), &w1s, &w1r);

    // stage field = x * screen: coalesced float4 loads -> swizzled LDS (row g
    // written and read by the same quad -> same wave -> no barrier needed)
    {
        const float4* xp = (const float4*)(x   + (size_t)b * 4096 + tid * 16);
        const float4* rp = (const float4*)(sre + (size_t)m * 4096 + tid * 16);
        const float4* ip = (const float4*)(sim + (size_t)m * 4096 + tid * 16);
#pragma unroll
        for (int a = 0; a < 4; a++) {
            float4 xv = xp[a], rv = rp[a], iv = ip[a];
            const float xa[4] = {xv.x, xv.y, xv.z, xv.w};
            const float ra[4] = {rv.x, rv.y, rv.z, rv.w};
            const float ia[4] = {iv.x, iv.y, iv.z, iv.w};
#pragma unroll
            for (int w = 0; w < 4; w++)
                xb2[sw(g, 16 * t + 4 * a + w)] = make_float2(xa[w] * ra[w], xa[w] * ia[w]);
        }
    }
    float xr[16], xi[16];
#pragma unroll
    for (int j = 0; j < 16; j++) {
        float2 v = xb2[sw(g, 4 * j + t)];
        xr[j] = v.x; xi[j] = v.y;
    }
    __syncthreads();   // barrier #1: publishes hx2/hy2 (staging is quad-local)

#pragma unroll 1
    for (int l = 0; l < NL; l++) {
        // phase factor: precomputed cos/sin, per-thread-contiguous float2[16]
        const float4* csp = (const float4*)(ws + ((l * 256 + tid) << 4));
#pragma unroll
        for (int q = 0; q < 8; q++) {
            float4 c4 = csp[q];
            cmul(xr[2 * q],     xi[2 * q],     c4.x, c4.y);
            cmul(xr[2 * q + 1], xi[2 * q + 1], c4.z, c4.w);
        }
        // FFT along x, * Hx
        fwd64(xr, xi, w1r, w1s, t);
#pragma unroll
        for (int i = 0; i < 16; i++) {
            const int kk = rev4(i) + 16 * sig;
            float2 h = hx2[kk];
            cmul(xr[i], xi[i], h.x, h.y);
        }
        // transpose #1 (write addrs = T2-read addrs of prev layer: no extra bar)
#pragma unroll
        for (int i = 0; i < 16; i++) {
            const int kk = rev4(i) + 16 * sig;
            xb2[sw(g, kk)] = make_float2(xr[i], xi[i]);
        }
        __syncthreads();
#pragma unroll
        for (int j = 0; j < 16; j++) {
            float2 v = xb2[sw(4 * j + t, g)];
            xr[j] = v.x; xi[j] = v.y;
        }
        // FFT along y, * Hy (e^{ikD} + 1/4096 folded), inverse FFT along y
        fwd64(xr, xi, w1r, w1s, t);
#pragma unroll
        for (int i = 0; i < 16; i++) {
            const int kk = rev4(i) + 16 * sig;
            float2 h = hy2[kk];
            cmul(xr[i], xi[i], h.x, h.y);
        }
        inv64(xr, xi, w1r, w1s, t);
        // transpose #2 (write addrs == own T1-read addrs: no bar before write)
#pragma unroll
        for (int j = 0; j < 16; j++)
            xb2[sw(4 * j + t, g)] = make_float2(xr[j], xi[j]);
        __syncthreads();
#pragma unroll
        for (int i = 0; i < 16; i++) {
            const int kk = rev4(i) + 16 * sig;
            float2 v = xb2[sw(g, kk)];
            xr[i] = v.x; xi[i] = v.y;
        }
        // inverse FFT along x -> natural spatial order for next layer
        inv64(xr, xi, w1r, w1s, t);
    }

    // intensity -> LDS (row g is quad-private: same wave, in-order -> no barrier)
    float* xbf = (float*)xb2;
#pragma unroll
    for (int j = 0; j < 16; j++)
        xbf[sw(g, 4 * j + t)] = xr[j] * xr[j] + xi[j] * xi[j];

    float iv[16];
#pragma unroll
    for (int k = 0; k < 16; k++)
        iv[k] = xbf[sw(g, 16 * t + k)];   // element e = tid*16 + k

    float part[NCLS];
#pragma unroll
    for (int c2 = 0; c2 < NCLS; c2++) part[c2] = 0.f;
#pragma unroll
    for (int c2 = 0; c2 < NCLS; c2++) {
        const float4* wp = (const float4*)(fcw + (size_t)c2 * 4096 + tid * 16);
#pragma unroll
        for (int a = 0; a < 4; a++) {
            float4 w4 = wp[a];
            part[c2] = fmaf(iv[4 * a + 0], w4.x, part[c2]);
            part[c2] = fmaf(iv[4 * a + 1], w4.y, part[c2]);
            part[c2] = fmaf(iv[4 * a + 2], w4.z, part[c2]);
            part[c2] = fmaf(iv[4 * a + 3], w4.w, part[c2]);
        }
    }
#pragma unroll
    for (int c2 = 0; c2 < NCLS; c2++) {
        float v = part[c2];
#pragma unroll
        for (int off = 32; off >= 1; off >>= 1) v += __shfl_down(v, off);
        if ((tid & 63) == 0) atomicAdd(&out[b * NCLS + c2], v * (1.0f / (float)NM));
    }
    if (m == 0 && tid < NCLS) atomicAdd(&out[b * NCLS + tid], fcb[tid]);
}

extern "C" void kernel_launch(void* const* d_in, const int* in_sizes, int n_in,
                              void* d_out, int out_size, void* d_ws, size_t ws_size,
                              hipStream_t stream) {
    const float* x   = (const float*)d_in[0];
    const float* sre = (const float*)d_in[1];
    const float* sim = (const float*)d_in[2];
    const float* ph  = (const float*)d_in[3];
    const float* fcw = (const float*)d_in[4];
    const float* fcb = (const float*)d_in[5];
    float* out = (float*)d_out;
    float2* ws = (float2*)d_ws;   // NL*4096 cs + 64 Hx + 64 Hy float2 (~100 KB)

    hipMemsetAsync(out, 0, (size_t)(NB * NCLS) * sizeof(float), stream);
    donn_tables<<<48, 256, 0, stream>>>(ph, ws);
    donn_main<<<NM * NB, 256, 0, stream>>>(x, sre, sim, ws, fcw, fcb, out);
}

// Round 5
// 408.776 us; speedup vs baseline: 1.3426x; 1.3426x over previous
//
#include <hip/hip_runtime.h>
#include <math.h>

#define NM   50
#define NB   128
#define NL   3
#define NCLS 10

#define PI_D        3.14159265358979323846264338327950288
#define TWO_PI_D    6.28318530717958647692528676655900577
#define INV_2PI_D   0.159154943091895335768883763372514362
#define LAMBDA_D    5.32e-07
#define DIST_D      0.035
#define PLD_D       (PI_D * LAMBDA_D * DIST_D)
#define KD_D        (TWO_PI_D / LAMBDA_D * DIST_D)

// exchange-buffer swizzle: element (r,c) at r*64 + (c ^ PS(r)) -> both
// transpose access patterns are exactly 2-way (free) on 32 banks.
#define PS(r) ((((r) & 15)) ^ ((((r) & 1)) << 4))
// intensity-buffer swizzle (write natural-per-quad, read row-contiguous)
#define QS(r) ((((r) & 15)) << 1)

__device__ __forceinline__ constexpr int rev4(int i) {
    return ((i & 1) << 3) | ((i & 2) << 1) | ((i & 4) >> 1) | ((i & 8) >> 3);
}

__device__ __forceinline__ float dppx1(float v) {  // lane ^ 1 within quad
    return __int_as_float(__builtin_amdgcn_mov_dpp(__float_as_int(v), 0xB1, 0xF, 0xF, true));
}
__device__ __forceinline__ float dppx2(float v) {  // lane ^ 2 within quad
    return __int_as_float(__builtin_amdgcn_mov_dpp(__float_as_int(v), 0x4E, 0xF, 0xF, true));
}

__device__ __forceinline__ void cmul(float& ar, float& ai, float wr, float wi) {
    float r = ar * wr - ai * wi;
    ai = ar * wi + ai * wr;
    ar = r;
}

__device__ __forceinline__ constexpr float c16t(int tw) {
    return (tw == 1) ? 0.923879532511286756f : (tw == 2) ? 0.707106781186547524f :
           (tw == 3) ? 0.382683432365089772f : (tw == 5) ? -0.382683432365089772f :
           (tw == 6) ? -0.707106781186547524f : (tw == 7) ? -0.923879532511286756f : 1.0f;
}
__device__ __forceinline__ constexpr float s16t(int tw) {
    return (tw == 1) ? 0.382683432365089772f : (tw == 2) ? 0.707106781186547524f :
           (tw == 3) ? 0.923879532511286756f : (tw == 5) ? 0.923879532511286756f :
           (tw == 6) ? 0.707106781186547524f : (tw == 7) ? 0.382683432365089772f : 0.0f;
}

// in-place DIF-16, natural in, bit-reversed out (pos i holds X[rev4(i)]), e^{-i}.
__device__ __forceinline__ void dif16_fwd(float* xr, float* xi) {
#pragma unroll
    for (int len = 8; len >= 1; len >>= 1) {
#pragma unroll
        for (int base = 0; base < 16; base += 2 * len) {
#pragma unroll
            for (int j = 0; j < len; j++) {
                const int i0 = base + j, i1 = i0 + len;
                const int tw = j * (8 / len);
                float ar = xr[i0], ai = xi[i0];
                float br = xr[i1], bi = xi[i1];
                xr[i0] = ar + br; xi[i0] = ai + bi;
                float dr = ar - br, di = ai - bi;
                if (tw == 0)      { xr[i1] = dr;  xi[i1] = di; }
                else if (tw == 4) { xr[i1] = di;  xi[i1] = -dr; }           // * (-i)
                else { xr[i1] = dr * c16t(tw) - di * (-s16t(tw));
                       xi[i1] = dr * (-s16t(tw)) + di * c16t(tw); }
            }
        }
    }
}

// in-place DIT-16, bit-reversed in, natural out, e^{+i}, unscaled.
__device__ __forceinline__ void dit16_inv(float* xr, float* xi) {
#pragma unroll
    for (int len = 1; len <= 8; len <<= 1) {
#pragma unroll
        for (int base = 0; base < 16; base += 2 * len) {
#pragma unroll
            for (int j = 0; j < len; j++) {
                const int i0 = base + j, i1 = i0 + len;
                const int tw = j * (8 / len);
                float br = xr[i1], bi = xi[i1];
                if (tw == 4)      { float tp = br; br = -bi; bi = tp; }     // * (+i)
                else if (tw != 0) { float r = br * c16t(tw) - bi * s16t(tw);
                                    bi = br * s16t(tw) + bi * c16t(tw); br = r; }
                float ar = xr[i0], ai = xi[i0];
                xr[i0] = ar + br; xi[i0] = ai + bi;
                xr[i1] = ar - br; xi[i1] = ai - bi;
            }
        }
    }
}

// forward cross-quad 4-pt DFT: stage xor2, lane3 *(-i), stage xor1.
__device__ __forceinline__ void quad_fwd(float* xr, float* xi, int t) {
    const float s2 = (t & 2) ? -1.f : 1.f;
    const float s1 = (t & 1) ? -1.f : 1.f;
    const bool l3 = (t == 3);
#pragma unroll
    for (int i = 0; i < 16; i++) {
        float pr = dppx2(xr[i]), pi = dppx2(xi[i]);
        float r = fmaf(xr[i], s2, pr), m = fmaf(xi[i], s2, pi);
        float r2 = l3 ? m : r, m2 = l3 ? -r : m;
        pr = dppx1(r2); pi = dppx1(m2);
        xr[i] = fmaf(r2, s1, pr); xi[i] = fmaf(m2, s1, pi);
    }
}

// inverse cross-quad 4-pt DFT: stage xor1, lane3 *(+i), stage xor2 (unscaled).
__device__ __forceinline__ void quad_inv(float* xr, float* xi, int t) {
    const float s2 = (t & 2) ? -1.f : 1.f;
    const float s1 = (t & 1) ? -1.f : 1.f;
    const bool l3 = (t == 3);
#pragma unroll
    for (int i = 0; i < 16; i++) {
        float pr = dppx1(xr[i]), pi = dppx1(xi[i]);
        float r = fmaf(xr[i], s1, pr), m = fmaf(xi[i], s1, pi);
        float r2 = l3 ? -m : r, m2 = l3 ? r : m;
        pr = dppx2(r2); pi = dppx2(m2);
        xr[i] = fmaf(r2, s2, pr); xi[i] = fmaf(m2, s2, pi);
    }
}

// 64-pt forward: reg i, lane t -> X[rev4(i)+16*sig]; twiddles from float2 LDS
// table (4 distinct addrs per wave -> broadcast, conflict-free), k=0 skipped.
__device__ __forceinline__ void fwd64(float* xr, float* xi, const float2* w64t, int t) {
    dif16_fwd(xr, xi);
#pragma unroll
    for (int i = 1; i < 16; i++) {
        float2 w = w64t[t * rev4(i)];
        cmul(xr[i], xi[i], w.x, -w.y);
    }
    quad_fwd(xr, xi, t);
}
__device__ __forceinline__ void inv64(float* xr, float* xi, const float2* w64t, int t) {
    quad_inv(xr, xi, t);
#pragma unroll
    for (int i = 1; i < 16; i++) {
        float2 w = w64t[t * rev4(i)];
        cmul(xr[i], xi[i], w.x, w.y);
    }
    dit16_inv(xr, xi);
}

__global__ __launch_bounds__(256) void donn_main(
    const float* __restrict__ x,
    const float* __restrict__ sre,
    const float* __restrict__ sim,
    const float* __restrict__ phase,
    const float* __restrict__ fcw,
    const float* __restrict__ fcb,
    float* __restrict__ out)
{
    __shared__ float xbr[4096];
    __shared__ float xbi[4096];
    __shared__ float2 w64t[64];
    __shared__ float2 hx2[64], hy2[64];

    const int tid = threadIdx.x;
    const int bid = blockIdx.x;
    const int b = bid & (NB - 1);
    const int m = bid >> 7;
    const int g = tid >> 2, t = tid & 3;
    const int sig = ((t & 1) << 1) | (t >> 1);

    if (tid < 64) {
        float s, c;
        __sincosf((float)tid * (float)(TWO_PI_D / 64.0), &s, &c);
        w64t[tid] = make_float2(c, s);
        double f = (double)((tid < 32) ? tid : tid - 64) * 15625.0;
        double phd = -PLD_D * f * f;
        double r1 = phd - TWO_PI_D * rint(phd * INV_2PI_D);
        hx2[tid] = make_float2(cosf((float)r1), sinf((float)r1));
        double r2 = phd + KD_D;                       // fold e^{ikD} into Hy
        r2 = r2 - TWO_PI_D * rint(r2 * INV_2PI_D);
        hy2[tid] = make_float2(cosf((float)r2) * (1.0f / 4096.0f),   // fold ifft2 scale
                               sinf((float)r2) * (1.0f / 4096.0f));
    }

    // stage field = x * screen straight into registers (cols 4j+t of row g)
    float xr[16], xi[16];
    {
        const float* xb = x   + b * 4096 + g * 64 + t;
        const float* sr = sre + m * 4096 + g * 64 + t;
        const float* si = sim + m * 4096 + g * 64 + t;
#pragma unroll
        for (int j = 0; j < 16; j++) {
            float xv = xb[4 * j];
            xr[j] = xv * sr[4 * j];
            xi[j] = xv * si[4 * j];
        }
    }
    __syncthreads();   // barrier #1: publishes w64t/hx2/hy2

    const int psg = PS(g);

#pragma unroll 1
    for (int l = 0; l < NL; l++) {
        // multiply exp(i*phase_l) (natural order in regs)
        const float* ph = phase + l * 4096 + g * 64 + t;
#pragma unroll
        for (int j = 0; j < 16; j++) {
            float s, c;
            __sincosf(ph[4 * j], &s, &c);
            cmul(xr[j], xi[j], c, s);
        }
        // FFT along x, * Hx
        fwd64(xr, xi, w64t, t);
#pragma unroll
        for (int i = 0; i < 16; i++) {
            const int kk = rev4(i) + 16 * sig;
            float2 h = hx2[kk];
            cmul(xr[i], xi[i], h.x, h.y);
        }
        // transpose #1 write (cells (g,kk): own T2-read set of prev layer -> no
        // pre-barrier needed; cells are thread-unique)
#pragma unroll
        for (int i = 0; i < 16; i++) {
            const int kk = rev4(i) + 16 * sig;
            const int a = g * 64 + (kk ^ psg);
            xbr[a] = xr[i]; xbi[a] = xi[i];
        }
        __syncthreads();
#pragma unroll
        for (int j = 0; j < 16; j++) {
            const int n = 4 * j + t;
            const int a = n * 64 + (g ^ PS(n));
            xr[j] = xbr[a]; xi[j] = xbi[a];
        }
        // FFT along y, * Hy (e^{ikD} + 1/4096 folded), inverse FFT along y
        fwd64(xr, xi, w64t, t);
#pragma unroll
        for (int i = 0; i < 16; i++) {
            const int kk = rev4(i) + 16 * sig;
            float2 h = hy2[kk];
            cmul(xr[i], xi[i], h.x, h.y);
        }
        inv64(xr, xi, w64t, t);
        // transpose #2 write (cells (n,g): own T1-read set -> no pre-barrier)
#pragma unroll
        for (int j = 0; j < 16; j++) {
            const int n = 4 * j + t;
            const int a = n * 64 + (g ^ PS(n));
            xbr[a] = xr[j]; xbi[a] = xi[j];
        }
        __syncthreads();
#pragma unroll
        for (int i = 0; i < 16; i++) {
            const int kk = rev4(i) + 16 * sig;
            const int a = g * 64 + (kk ^ psg);
            xr[i] = xbr[a]; xi[i] = xbi[a];
        }
        // inverse FFT along x -> natural spatial order for next layer
        inv64(xr, xi, w64t, t);
    }

    // intensity -> LDS row g (quad-local, same wave in lockstep -> no barrier:
    // the T2-reads of row g were issued by this same wave before these writes)
    const int qsg = QS(g);
#pragma unroll
    for (int j = 0; j < 16; j++) {
        const int c0 = 4 * j + t;
        xbr[g * 64 + (c0 ^ qsg)] = xr[j] * xr[j] + xi[j] * xi[j];
    }
    __syncthreads();   // pre-FC barrier (FC reads cross rows)

    float ivl[16];
#pragma unroll
    for (int i = 0; i < 16; i++) {
        const int e = i * 256 + tid;
        const int r = e >> 6, c = e & 63;
        ivl[i] = xbr[r * 64 + (c ^ QS(r))];
    }
    float part[NCLS];
#pragma unroll
    for (int c2 = 0; c2 < NCLS; c2++) part[c2] = 0.f;
#pragma unroll
    for (int c2 = 0; c2 < NCLS; c2++) {
        const float* wrow = fcw + c2 * 4096 + tid;
#pragma unroll
        for (int i = 0; i < 16; i++)
            part[c2] = fmaf(ivl[i], wrow[i * 256], part[c2]);
    }
#pragma unroll
    for (int c2 = 0; c2 < NCLS; c2++) {
        float v = part[c2];
#pragma unroll
        for (int off = 32; off >= 1; off >>= 1) v += __shfl_down(v, off);
        if ((tid & 63) == 0) atomicAdd(&out[b * NCLS + c2], v * (1.0f / (float)NM));
    }
    if (m == 0 && tid < NCLS) atomicAdd(&out[b * NCLS + tid], fcb[tid]);
}

extern "C" void kernel_launch(void* const* d_in, const int* in_sizes, int n_in,
                              void* d_out, int out_size, void* d_ws, size_t ws_size,
                              hipStream_t stream) {
    const float* x   = (const float*)d_in[0];
    const float* sre = (const float*)d_in[1];
    const float* sim = (const float*)d_in[2];
    const float* ph  = (const float*)d_in[3];
    const float* fcw = (const float*)d_in[4];
    const float* fcb = (const float*)d_in[5];
    float* out = (float*)d_out;

    hipMemsetAsync(out, 0, (size_t)(NB * NCLS) * sizeof(float), stream);
    donn_main<<<NM * NB, 256, 0, stream>>>(x, sre, sim, ph, fcw, fcb, out);
}

// Round 7
// 305.543 us; speedup vs baseline: 1.7962x; 1.3379x over previous
//
#include <hip/hip_runtime.h>
#include <math.h>

#define NM   50
#define NB   128
#define NL   3
#define NCLS 10

#define PI_D        3.14159265358979323846264338327950288
#define TWO_PI_D    6.28318530717958647692528676655900577
#define INV_2PI_D   0.159154943091895335768883763372514362
#define LAMBDA_D    5.32e-07
#define DIST_D      0.035
#define PLD_D       (PI_D * LAMBDA_D * DIST_D)
#define KD_D        (TWO_PI_D / LAMBDA_D * DIST_D)

typedef float f2 __attribute__((ext_vector_type(2)));

__device__ __forceinline__ f2 mkf2(float a, float b) { f2 r; r.x = a; r.y = b; return r; }

// Unified LDS swizzle (R4-proven, measured 0.98e7 conflicts): element (r,c) at
// r*64 + (c ^ ((r&3)<<2) ^ ((c>>4)&3)).
__device__ __forceinline__ int sw(int r, int c) {
    return r * 64 + (c ^ (((r & 3) << 2) ^ ((c >> 4) & 3)));
}
// intensity-buffer swizzle (write natural-per-quad, read row-contiguous)
#define QS(r) ((((r) & 15)) << 1)

__device__ __forceinline__ constexpr int rev4(int i) {
    return ((i & 1) << 3) | ((i & 2) << 1) | ((i & 4) >> 1) | ((i & 8) >> 3);
}

__device__ __forceinline__ float dppx1(float v) {  // lane ^ 1 within quad
    return __int_as_float(__builtin_amdgcn_mov_dpp(__float_as_int(v), 0xB1, 0xF, 0xF, true));
}
__device__ __forceinline__ float dppx2(float v) {  // lane ^ 2 within quad
    return __int_as_float(__builtin_amdgcn_mov_dpp(__float_as_int(v), 0x4E, 0xF, 0xF, true));
}

// ---- complex primitives as f2 vector expressions (compiler picks VOP3P) ----
// d = a * w : (ax*wr - ay*wi, ay*wr + ax*wi)
__device__ __forceinline__ f2 cmul(f2 a, f2 w) {
    return a * w.x + a.yx * mkf2(-w.y, w.y);
}
// d = a * conj(w) : (ax*wr + ay*wi, ay*wr - ax*wi)
__device__ __forceinline__ f2 cmulc(f2 a, f2 w) {
    return a * w.x + a.yx * mkf2(w.y, -w.y);
}

__device__ __forceinline__ constexpr float c16t(int tw) {
    return (tw == 1) ? 0.923879532511286756f : (tw == 2) ? 0.707106781186547524f :
           (tw == 3) ? 0.382683432365089772f : (tw == 5) ? -0.382683432365089772f :
           (tw == 6) ? -0.707106781186547524f : (tw == 7) ? -0.923879532511286756f : 1.0f;
}
__device__ __forceinline__ constexpr float s16t(int tw) {
    return (tw == 1) ? 0.382683432365089772f : (tw == 2) ? 0.707106781186547524f :
           (tw == 3) ? 0.923879532511286756f : (tw == 5) ? 0.923879532511286756f :
           (tw == 6) ? 0.707106781186547524f : (tw == 7) ? 0.382683432365089772f : 0.0f;
}

// in-place DIF-16, natural in, bit-reversed out (pos i holds X[rev4(i)]), e^{-i}.
// twiddle W16^tw = (c, -s): d*(c,-s) = d*c + d.yx*(s,-s)
__device__ __forceinline__ void dif16_fwd(f2* x) {
#pragma unroll
    for (int len = 8; len >= 1; len >>= 1) {
#pragma unroll
        for (int base = 0; base < 16; base += 2 * len) {
#pragma unroll
            for (int j = 0; j < len; j++) {
                const int i0 = base + j, i1 = i0 + len;
                const int tw = j * (8 / len);
                f2 a = x[i0], b = x[i1];
                x[i0] = a + b;
                f2 d = a - b;
                if (tw == 0)      { x[i1] = d; }
                else if (tw == 4) { x[i1] = mkf2(d.y, -d.x); }              // * (-i)
                else {
                    const float c = c16t(tw), s = s16t(tw);
                    x[i1] = d * c + d.yx * mkf2(s, -s);
                }
            }
        }
    }
}

// in-place DIT-16, bit-reversed in, natural out, e^{+i}, unscaled.
// twiddle (c, +s): b*(c,s) = b*c + b.yx*(-s, s)
__device__ __forceinline__ void dit16_inv(f2* x) {
#pragma unroll
    for (int len = 1; len <= 8; len <<= 1) {
#pragma unroll
        for (int base = 0; base < 16; base += 2 * len) {
#pragma unroll
            for (int j = 0; j < len; j++) {
                const int i0 = base + j, i1 = i0 + len;
                const int tw = j * (8 / len);
                f2 a = x[i0], b = x[i1];
                if (tw == 4)      { b = mkf2(-b.y, b.x); }                  // * (+i)
                else if (tw != 0) {
                    const float c = c16t(tw), s = s16t(tw);
                    b = b * c + b.yx * mkf2(-s, s);
                }
                x[i0] = a + b;
                x[i1] = a - b;
            }
        }
    }
}

// forward cross-quad 4-pt DFT: stage xor2, lane3 *(-i), stage xor1.
__device__ __forceinline__ void quad_fwd(f2* x, float s1, float s2, bool l3) {
#pragma unroll
    for (int i = 0; i < 16; i++) {
        f2 p = mkf2(dppx2(x[i].x), dppx2(x[i].y));
        f2 r = x[i] * s2 + p;
        f2 r2 = l3 ? mkf2(r.y, -r.x) : r;
        f2 q = mkf2(dppx1(r2.x), dppx1(r2.y));
        x[i] = r2 * s1 + q;
    }
}

// inverse cross-quad 4-pt DFT: stage xor1, lane3 *(+i), stage xor2 (unscaled).
__device__ __forceinline__ void quad_inv(f2* x, float s1, float s2, bool l3) {
#pragma unroll
    for (int i = 0; i < 16; i++) {
        f2 p = mkf2(dppx1(x[i].x), dppx1(x[i].y));
        f2 r = x[i] * s1 + p;
        f2 r2 = l3 ? mkf2(-r.y, r.x) : r;
        f2 q = mkf2(dppx2(r2.x), dppx2(r2.y));
        x[i] = r2 * s2 + q;
    }
}

// 64-pt forward: reg i, lane t -> X[rev4(i)+16*sig]; twiddles from f2 LDS table.
__device__ __forceinline__ void fwd64(f2* x, const f2* w64t, int t, float s1, float s2, bool l3) {
    dif16_fwd(x);
#pragma unroll
    for (int i = 1; i < 16; i++) x[i] = cmulc(x[i], w64t[t * rev4(i)]);
    quad_fwd(x, s1, s2, l3);
}
__device__ __forceinline__ void inv64(f2* x, const f2* w64t, int t, float s1, float s2, bool l3) {
    quad_inv(x, s1, s2, l3);
#pragma unroll
    for (int i = 1; i < 16; i++) x[i] = cmul(x[i], w64t[t * rev4(i)]);
    dit16_inv(x);
}

__global__ __launch_bounds__(256) void donn_main(
    const float* __restrict__ x,
    const float* __restrict__ sre,
    const float* __restrict__ sim,
    const float* __restrict__ phase,
    const float* __restrict__ fcw,
    const float* __restrict__ fcb,
    float* __restrict__ out)
{
    __shared__ f2 xb2[4096];
    __shared__ f2 w64t[64];
    __shared__ f2 hx2[64], hy2[64];

    const int tid = threadIdx.x;
    const int bid = blockIdx.x;
    const int b = bid & (NB - 1);
    const int m = bid >> 7;
    const int g = tid >> 2, t = tid & 3;
    const int sig = ((t & 1) << 1) | (t >> 1);
    const bool l3 = (t == 3);
    const float s1 = (t & 1) ? -1.f : 1.f;
    const float s2 = (t & 2) ? -1.f : 1.f;

    if (tid < 64) {
        float s, c;
        __sincosf((float)tid * (float)(TWO_PI_D / 64.0), &s, &c);
        w64t[tid] = mkf2(c, s);
        double f = (double)((tid < 32) ? tid : tid - 64) * 15625.0;
        double phd = -PLD_D * f * f;
        double r1 = phd - TWO_PI_D * rint(phd * INV_2PI_D);
        hx2[tid] = mkf2(cosf((float)r1), sinf((float)r1));
        double r2 = phd + KD_D;                       // fold e^{ikD} into Hy
        r2 = r2 - TWO_PI_D * rint(r2 * INV_2PI_D);
        hy2[tid] = mkf2(cosf((float)r2) * (1.0f / 4096.0f),   // fold ifft2 scale
                        sinf((float)r2) * (1.0f / 4096.0f));
    }

    // stage field = x * screen straight into registers (cols 4j+t of row g)
    f2 X[16];
    {
        const float* xb = x   + b * 4096 + g * 64 + t;
        const float* sr = sre + m * 4096 + g * 64 + t;
        const float* si = sim + m * 4096 + g * 64 + t;
#pragma unroll
        for (int j = 0; j < 16; j++) {
            float xv = xb[4 * j];
            X[j].x = xv * sr[4 * j];
            X[j].y = xv * si[4 * j];
        }
    }
    __syncthreads();   // publishes w64t/hx2/hy2

#pragma unroll 1
    for (int l = 0; l < NL; l++) {
        // multiply exp(i*phase_l) (natural order in regs)
        const float* ph = phase + l * 4096 + g * 64 + t;
#pragma unroll
        for (int j = 0; j < 16; j++) {
            float s, c;
            __sincosf(ph[4 * j], &s, &c);
            X[j] = cmul(X[j], mkf2(c, s));
        }
        // FFT along x, * Hx
        fwd64(X, w64t, t, s1, s2, l3);
#pragma unroll
        for (int i = 0; i < 16; i++) {
            const int kk = rev4(i) + 16 * sig;
            X[i] = cmul(X[i], hx2[kk]);
        }
        // transpose #1 write (cells (g,kk) == own T2-read set of prev layer and
        // thread-unique -> no pre-barrier; b64 ops)
#pragma unroll
        for (int i = 0; i < 16; i++) {
            const int kk = rev4(i) + 16 * sig;
            xb2[sw(g, kk)] = X[i];
        }
        __syncthreads();
#pragma unroll
        for (int j = 0; j < 16; j++)
            X[j] = xb2[sw(4 * j + t, g)];
        // FFT along y, * Hy (e^{ikD} + 1/4096 folded), inverse FFT along y
        fwd64(X, w64t, t, s1, s2, l3);
#pragma unroll
        for (int i = 0; i < 16; i++) {
            const int kk = rev4(i) + 16 * sig;
            X[i] = cmul(X[i], hy2[kk]);
        }
        inv64(X, w64t, t, s1, s2, l3);
        // transpose #2 write (cells (n,g) == own T1-read set -> no pre-barrier)
#pragma unroll
        for (int j = 0; j < 16; j++)
            xb2[sw(4 * j + t, g)] = X[j];
        __syncthreads();
#pragma unroll
        for (int i = 0; i < 16; i++) {
            const int kk = rev4(i) + 16 * sig;
            X[i] = xb2[sw(g, kk)];
        }
        // inverse FFT along x -> natural spatial order for next layer
        inv64(X, w64t, t, s1, s2, l3);
    }

    // intensity -> float view of xb2 (QS layout). Barrier first: float rows
    // alias f2 rows that OTHER waves just T2-read.
    __syncthreads();
    float* xbf = (float*)xb2;
    const int qsg = QS(g);
#pragma unroll
    for (int j = 0; j < 16; j++) {
        const int c0 = 4 * j + t;
        xbf[g * 64 + (c0 ^ qsg)] = fmaf(X[j].x, X[j].x, X[j].y * X[j].y);
    }
    __syncthreads();   // pre-FC barrier (FC reads cross rows)

    float ivl[16];
#pragma unroll
    for (int i = 0; i < 16; i++) {
        const int e = i * 256 + tid;
        const int r = e >> 6, c = e & 63;
        ivl[i] = xbf[r * 64 + (c ^ QS(r))];
    }
    float part[NCLS];
#pragma unroll
    for (int c2 = 0; c2 < NCLS; c2++) part[c2] = 0.f;
#pragma unroll
    for (int c2 = 0; c2 < NCLS; c2++) {
        const float* wrow = fcw + c2 * 4096 + tid;
#pragma unroll
        for (int i = 0; i < 16; i++)
            part[c2] = fmaf(ivl[i], wrow[i * 256], part[c2]);
    }
#pragma unroll
    for (int c2 = 0; c2 < NCLS; c2++) {
        float v = part[c2];
#pragma unroll
        for (int off = 32; off >= 1; off >>= 1) v += __shfl_down(v, off);
        if ((tid & 63) == 0) atomicAdd(&out[b * NCLS + c2], v * (1.0f / (float)NM));
    }
    if (m == 0 && tid < NCLS) atomicAdd(&out[b * NCLS + tid], fcb[tid]);
}

extern "C" void kernel_launch(void* const* d_in, const int* in_sizes, int n_in,
                              void* d_out, int out_size, void* d_ws, size_t ws_size,
                              hipStream_t stream) {
    const float* x   = (const float*)d_in[0];
    const float* sre = (const float*)d_in[1];
    const float* sim = (const float*)d_in[2];
    const float* ph  = (const float*)d_in[3];
    const float* fcw = (const float*)d_in[4];
    const float* fcb = (const float*)d_in[5];
    float* out = (float*)d_out;

    hipMemsetAsync(out, 0, (size_t)(NB * NCLS) * sizeof(float), stream);
    donn_main<<<NM * NB, 256, 0, stream>>>(x, sre, sim, ph, fcw, fcb, out);
}